// Round 1
// baseline (3061.942 us; speedup 1.0000x reference)
//
#include <hip/hip_runtime.h>
#include <hip/hip_bf16.h>
#include <math.h>

#define B_N    32768
#define XD     60
#define YD     10
#define NK     64
#define HID    2048
#define OUTD   704   // NK + NK*YD

// ---------------- labels: argmin_k ||y - c_k||^2  (ref formula, first-min ties)
__global__ __launch_bounds__(256) void k_labels(const float* __restrict__ y,
                                                const float* __restrict__ centers,
                                                int* __restrict__ labels,
                                                int* __restrict__ counts) {
    __shared__ float cs[NK * YD];
    __shared__ float sc[NK];
    int t = threadIdx.x;
    for (int idx = t; idx < NK * YD; idx += 256) cs[idx] = centers[idx];
    __syncthreads();
    if (t < NK) {
        float s = 0.f;
        for (int j = 0; j < YD; ++j) { float v = cs[t * YD + j]; s += v * v; }
        sc[t] = s;
    }
    __syncthreads();
    int i = blockIdx.x * 256 + t;
    if (i >= B_N) return;
    float ly[YD]; float sy = 0.f;
    for (int j = 0; j < YD; ++j) { ly[j] = y[i * YD + j]; sy += ly[j] * ly[j]; }
    float best = 1e30f; int lab = 0;
    for (int k = 0; k < NK; ++k) {
        float dot = 0.f;
        #pragma unroll
        for (int j = 0; j < YD; ++j) dot += ly[j] * cs[k * YD + j];
        float d = sy - 2.f * dot + sc[k];
        if (d < best) { best = d; lab = k; }
    }
    labels[i] = lab;
    atomicAdd(&counts[lab], 1);
}

// ---------------- serial exclusive scan over 64 counts (trivial)
__global__ void k_scan(const int* __restrict__ counts, int* __restrict__ offsets,
                       int* __restrict__ cursor) {
    if (threadIdx.x == 0) {
        int off = 0;
        for (int k = 0; k < NK; ++k) { offsets[k] = off; cursor[k] = off; off += counts[k]; }
    }
}

// ---------------- scatter rows into label-sorted order
__global__ __launch_bounds__(256) void k_scatter(const int* __restrict__ labels,
                                                 int* __restrict__ cursor,
                                                 int* __restrict__ perm) {
    int i = blockIdx.x * 256 + threadIdx.x;
    if (i >= B_N) return;
    int pos = atomicAdd(&cursor[labels[i]], 1);
    perm[pos] = i;
}

// ---------------- GEMM1: h = relu(x @ W1[10:70] + b1), stored bf16
#define G1R 64
#define G1C 128
__global__ __launch_bounds__(256) void k_gemm1(const float* __restrict__ x,
                                               const float* __restrict__ W1,
                                               const float* __restrict__ b1,
                                               __hip_bfloat16* __restrict__ h) {
    __shared__ float xs[G1R][XD + 1];      // 64 x 61
    __shared__ float wsm[XD][G1C + 4];     // 60 x 132 (pad mult of 4 for float4)
    int t = threadIdx.x;
    int row0 = blockIdx.x * G1R;
    int col0 = blockIdx.y * G1C;
    for (int idx = t; idx < G1R * XD; idx += 256) {
        int r = idx / XD, c = idx - r * XD;
        xs[r][c] = x[(row0 + r) * XD + c];
    }
    for (int idx = t; idx < XD * G1C; idx += 256) {
        int r = idx >> 7, c = idx & 127;
        wsm[r][c] = W1[(YD + r) * HID + col0 + c];
    }
    __syncthreads();
    int cg = t & 31, rg = t >> 5;
    int r0 = rg * 8, c0 = cg * 4;
    float acc[8][4];
    #pragma unroll
    for (int i = 0; i < 8; ++i)
        #pragma unroll
        for (int j = 0; j < 4; ++j) acc[i][j] = 0.f;
    for (int k = 0; k < XD; ++k) {
        float a[8];
        #pragma unroll
        for (int i = 0; i < 8; ++i) a[i] = xs[r0 + i][k];
        float4 b = *reinterpret_cast<const float4*>(&wsm[k][c0]);
        #pragma unroll
        for (int i = 0; i < 8; ++i) {
            acc[i][0] += a[i] * b.x; acc[i][1] += a[i] * b.y;
            acc[i][2] += a[i] * b.z; acc[i][3] += a[i] * b.w;
        }
    }
    float bb[4];
    #pragma unroll
    for (int j = 0; j < 4; ++j) bb[j] = b1[col0 + c0 + j];
    #pragma unroll
    for (int i = 0; i < 8; ++i) {
        ushort4 pk;
        float v0 = fmaxf(acc[i][0] + bb[0], 0.f);
        float v1 = fmaxf(acc[i][1] + bb[1], 0.f);
        float v2 = fmaxf(acc[i][2] + bb[2], 0.f);
        float v3 = fmaxf(acc[i][3] + bb[3], 0.f);
        __hip_bfloat16 t0 = __float2bfloat16(v0), t1 = __float2bfloat16(v1);
        __hip_bfloat16 t2 = __float2bfloat16(v2), t3 = __float2bfloat16(v3);
        pk.x = *reinterpret_cast<unsigned short*>(&t0);
        pk.y = *reinterpret_cast<unsigned short*>(&t1);
        pk.z = *reinterpret_cast<unsigned short*>(&t2);
        pk.w = *reinterpret_cast<unsigned short*>(&t3);
        *reinterpret_cast<ushort4*>(&h[(size_t)(row0 + r0 + i) * HID + col0 + c0]) = pk;
    }
}

// ---------------- main fused kernel: per (group, row-tile): logits+res GEMM,
// log-softmax CE, residual MSE -> atomic partial sums
#define KC 64
__global__ __launch_bounds__(256) void k_main(const __hip_bfloat16* __restrict__ h,
                                              const float* __restrict__ W2,
                                              const float* __restrict__ b2,
                                              const float* __restrict__ y,
                                              const float* __restrict__ centers,
                                              const int* __restrict__ counts,
                                              const int* __restrict__ offsets,
                                              const int* __restrict__ perm,
                                              float* __restrict__ accum) {
    __shared__ float hs[64][KC + 1];   // 64 rows x 64 k
    __shared__ float wsm[KC][84];      // 64 k x 80 cols (64 logits + 10 res + 6 pad)
    __shared__ int   rows_s[64];
    __shared__ float red_ce[64], red_mse[64];
    int g   = blockIdx.x;
    int n_g = counts[g];
    int off = offsets[g];
    int t   = threadIdx.x;
    int rg = t >> 4, cg = t & 15;
    int r0 = rg * 4, c0 = cg * 5;

    for (int tile = blockIdx.y; tile * 64 < n_g; tile += gridDim.y) {
        int base  = tile * 64;
        int nrows = min(64, n_g - base);
        if (t < 64) rows_s[t] = (t < nrows) ? perm[off + base + t] : -1;
        __syncthreads();

        float acc[4][5];
        #pragma unroll
        for (int i = 0; i < 4; ++i)
            #pragma unroll
            for (int j = 0; j < 5; ++j) acc[i][j] = 0.f;

        for (int k0 = 0; k0 < HID; k0 += KC) {
            for (int idx = t; idx < 64 * KC; idx += 256) {
                int r = idx >> 6, kk = idx & 63;
                int row = rows_s[r];
                hs[r][kk] = (row >= 0) ? __bfloat162float(h[(size_t)row * HID + k0 + kk]) : 0.f;
            }
            for (int idx = t; idx < KC * 80; idx += 256) {
                int kk = idx / 80, c = idx - kk * 80;
                const float* wrow = &W2[(size_t)(k0 + kk) * OUTD];
                float v;
                if (c < 64)       v = wrow[c];
                else if (c < 74)  v = wrow[64 + g * 10 + (c - 64)];
                else              v = 0.f;
                wsm[kk][c] = v;
            }
            __syncthreads();
            for (int kk = 0; kk < KC; ++kk) {
                float a[4];
                #pragma unroll
                for (int i = 0; i < 4; ++i) a[i] = hs[r0 + i][kk];
                float w[5];
                #pragma unroll
                for (int j = 0; j < 5; ++j) w[j] = wsm[kk][c0 + j];
                #pragma unroll
                for (int i = 0; i < 4; ++i)
                    #pragma unroll
                    for (int j = 0; j < 5; ++j) acc[i][j] += a[i] * w[j];
            }
            __syncthreads();
        }
        // write out tile (with bias) into wsm, reused as [64 rows][80 cols]
        #pragma unroll
        for (int i = 0; i < 4; ++i)
            #pragma unroll
            for (int j = 0; j < 5; ++j) {
                int c = c0 + j;
                float bias = 0.f;
                if (c < 64)      bias = b2[c];
                else if (c < 74) bias = b2[64 + g * 10 + (c - 64)];
                wsm[r0 + i][c] = acc[i][j] + bias;
            }
        __syncthreads();
        if (t < 64) {
            float ce_v = 0.f, mse_v = 0.f;
            if (t < nrows) {
                float m = -1e30f;
                for (int c = 0; c < 64; ++c) m = fmaxf(m, wsm[t][c]);
                float s = 0.f;
                for (int c = 0; c < 64; ++c) s += expf(wsm[t][c] - m);
                float lse = m + logf(s);
                ce_v = lse - wsm[t][g];
                int row = rows_s[t];
                #pragma unroll
                for (int j = 0; j < YD; ++j) {
                    float tr = y[row * YD + j] - centers[g * YD + j];
                    float d  = tr - wsm[t][64 + j];
                    mse_v += d * d;
                }
            }
            red_ce[t] = ce_v; red_mse[t] = mse_v;
        }
        __syncthreads();
        if (t == 0) {
            float sc = 0.f, sm = 0.f;
            for (int i = 0; i < 64; ++i) { sc += red_ce[i]; sm += red_mse[i]; }
            atomicAdd(&accum[0], sc);
            atomicAdd(&accum[1], sm);
        }
        __syncthreads();
    }
}

__global__ void k_final(const float* __restrict__ accum, float* __restrict__ out) {
    out[0] = accum[0] / (float)B_N + 100.f * accum[1] / ((float)B_N * (float)YD);
}

extern "C" void kernel_launch(void* const* d_in, const int* in_sizes, int n_in,
                              void* d_out, int out_size, void* d_ws, size_t ws_size,
                              hipStream_t stream) {
    const float* x       = (const float*)d_in[0];
    const float* y       = (const float*)d_in[1];
    const float* centers = (const float*)d_in[2];
    const float* W1      = (const float*)d_in[3];
    const float* b1      = (const float*)d_in[4];
    const float* W2      = (const float*)d_in[5];
    const float* b2      = (const float*)d_in[6];

    char* ws = (char*)d_ws;
    float* accum  = (float*)ws;                 // 2 floats
    int* counts   = (int*)(ws + 64);            // 64 ints
    int* offsets  = (int*)(ws + 320);
    int* cursor   = (int*)(ws + 576);
    int* labels   = (int*)(ws + 1024);          // B ints
    int* perm     = (int*)(ws + 1024 + 4 * B_N);
    __hip_bfloat16* h = (__hip_bfloat16*)(ws + 1024 + 8 * B_N + 1024); // bf16 [B][2048]

    hipMemsetAsync(ws, 0, 1024, stream);   // zero accum + counts each launch
    k_labels <<<B_N / 256, 256, 0, stream>>>(y, centers, labels, counts);
    k_scan   <<<1, 64, 0, stream>>>(counts, offsets, cursor);
    k_scatter<<<B_N / 256, 256, 0, stream>>>(labels, cursor, perm);
    k_gemm1  <<<dim3(B_N / G1R, HID / G1C), 256, 0, stream>>>(x, W1, b1, h);
    k_main   <<<dim3(NK, 8), 256, 0, stream>>>(h, W2, b2, y, centers, counts, offsets, perm, accum);
    k_final  <<<1, 1, 0, stream>>>(accum, (float*)d_out);
}

// Round 2
// 627.901 us; speedup vs baseline: 4.8765x; 4.8765x over previous
//
#include <hip/hip_runtime.h>
#include <hip/hip_bf16.h>
#include <math.h>

#define B_N    32768
#define XD     60
#define YD     10
#define NK     64
#define HID    2048
#define OUTD   704   // NK + NK*YD
#define TILES_Y 12

typedef __bf16 bf16x8_t __attribute__((ext_vector_type(8)));
typedef float  f32x4_t  __attribute__((ext_vector_type(4)));

union Frag { uint4 q; bf16x8_t v; };

__device__ __forceinline__ unsigned short bf16bits(float f) {
    __hip_bfloat16 h = __float2bfloat16(f);
    return *reinterpret_cast<unsigned short*>(&h);
}

// ---------------- labels: argmin_k ||y - c_k||^2  (ref formula, first-min ties)
__global__ __launch_bounds__(256) void k_labels(const float* __restrict__ y,
                                                const float* __restrict__ centers,
                                                int* __restrict__ labels,
                                                int* __restrict__ counts) {
    __shared__ float cs[NK * YD];
    __shared__ float sc[NK];
    int t = threadIdx.x;
    for (int idx = t; idx < NK * YD; idx += 256) cs[idx] = centers[idx];
    __syncthreads();
    if (t < NK) {
        float s = 0.f;
        for (int j = 0; j < YD; ++j) { float v = cs[t * YD + j]; s += v * v; }
        sc[t] = s;
    }
    __syncthreads();
    int i = blockIdx.x * 256 + t;
    if (i >= B_N) return;
    float ly[YD]; float sy = 0.f;
    for (int j = 0; j < YD; ++j) { ly[j] = y[i * YD + j]; sy += ly[j] * ly[j]; }
    float best = 1e30f; int lab = 0;
    for (int k = 0; k < NK; ++k) {
        float dot = 0.f;
        #pragma unroll
        for (int j = 0; j < YD; ++j) dot += ly[j] * cs[k * YD + j];
        float d = sy - 2.f * dot + sc[k];
        if (d < best) { best = d; lab = k; }
    }
    labels[i] = lab;
    atomicAdd(&counts[lab], 1);
}

__global__ void k_scan(const int* __restrict__ counts, int* __restrict__ offsets,
                       int* __restrict__ cursor) {
    if (threadIdx.x == 0) {
        int off = 0;
        for (int k = 0; k < NK; ++k) { offsets[k] = off; cursor[k] = off; off += counts[k]; }
    }
}

__global__ __launch_bounds__(256) void k_scatter(const int* __restrict__ labels,
                                                 int* __restrict__ cursor,
                                                 int* __restrict__ perm) {
    int i = blockIdx.x * 256 + threadIdx.x;
    if (i >= B_N) return;
    int pos = atomicAdd(&cursor[labels[i]], 1);
    perm[pos] = i;
}

// ---------------- W1T[n][k] = bf16(W1[10+k][n]), k in [0,64) padded past 60
__global__ __launch_bounds__(256) void k_w1t(const float* __restrict__ W1,
                                             unsigned short* __restrict__ W1T) {
    int n = blockIdx.x * 256 + threadIdx.x;
    #pragma unroll
    for (int k = 0; k < 64; ++k) {
        float v = (k < XD) ? W1[(size_t)(YD + k) * HID + n] : 0.f;
        W1T[(size_t)n * 64 + k] = bf16bits(v);
    }
}

// ---------------- W2T[c][k] = bf16(W2[k][c])  (704 x 2048 bf16)
__global__ __launch_bounds__(256) void k_w2t(const float* __restrict__ W2,
                                             unsigned short* __restrict__ W2T) {
    __shared__ float tile[32][33];
    int c0 = blockIdx.x * 32, k0 = blockIdx.y * 32;
    int tx = threadIdx.x & 31, ty = threadIdx.x >> 5;   // ty 0..7
    #pragma unroll
    for (int j = 0; j < 32; j += 8)
        tile[ty + j][tx] = W2[(size_t)(k0 + ty + j) * OUTD + c0 + tx];
    __syncthreads();
    #pragma unroll
    for (int j = 0; j < 32; j += 8)
        W2T[(size_t)(c0 + ty + j) * HID + k0 + tx] = bf16bits(tile[tx][ty + j]);
}

// ---------------- fused: per (group g, 64-row tile):
//   h_slab = relu(x@W1s+b1) [MFMA] -> LDS bf16 -> acc += h_slab@W2s [MFMA]
//   then log-softmax CE + residual MSE -> atomic partial sums
__global__ __launch_bounds__(256) void k_fused(const float* __restrict__ x,
                                               const unsigned short* __restrict__ W1T,
                                               const float* __restrict__ b1,
                                               const unsigned short* __restrict__ W2T,
                                               const float* __restrict__ b2,
                                               const float* __restrict__ y,
                                               const float* __restrict__ centers,
                                               const int* __restrict__ counts,
                                               const int* __restrict__ offsets,
                                               const int* __restrict__ perm,
                                               float* __restrict__ accum) {
    __shared__ __align__(16) unsigned short x_lds[64][72];   // bf16 bits, k padded to 64
    __shared__ __align__(16) unsigned short h_lds[64][136];  // bf16 bits, 128-wide slab
    __shared__ __align__(16) float out_lds[64][85];          // 80 cols used
    __shared__ int   rows_s[64];
    __shared__ float red_ce[64], red_mse[64];

    int g   = blockIdx.x;
    int n_g = counts[g];
    int off = offsets[g];
    int t   = threadIdx.x;
    int w   = t >> 6;          // wave 0..3
    int l   = t & 63;
    int lr  = l & 15;          // row/col-in-tile lane index
    int lg  = l >> 4;          // lane group 0..3

    // per-lane W2T row indices for the 5 output N-tiles (64 logits + 10 res + pad)
    int cmap[5];
    #pragma unroll
    for (int nt = 0; nt < 4; ++nt) cmap[nt] = 16 * nt + lr;
    cmap[4] = (lr < YD) ? (NK + g * YD + lr) : -1;

    for (int tile = blockIdx.y; tile * 64 < n_g; tile += TILES_Y) {
        int base  = tile * 64;
        int nrows = min(64, n_g - base);
        if (t < 64) rows_s[t] = (t < nrows) ? perm[off + base + t] : -1;
        __syncthreads();

        // gather x rows -> LDS bf16 (zero pad rows and k=60..63)
        for (int idx = t; idx < 64 * 64; idx += 256) {
            int r = idx >> 6, c = idx & 63;
            int row = rows_s[r];
            float v = (row >= 0 && c < XD) ? x[row * XD + c] : 0.f;
            x_lds[r][c] = bf16bits(v);
        }
        __syncthreads();

        // x A-fragments (held across all slabs): [m-tile 0..3][k-step 0..1]
        Frag xf[4][2];
        #pragma unroll
        for (int m = 0; m < 4; ++m)
            #pragma unroll
            for (int ks = 0; ks < 2; ++ks)
                xf[m][ks].q = *reinterpret_cast<const uint4*>(&x_lds[16 * m + lr][32 * ks + 8 * lg]);

        f32x4_t acc2[5];
        #pragma unroll
        for (int nt = 0; nt < 5; ++nt) acc2[nt] = (f32x4_t){0.f, 0.f, 0.f, 0.f};

        for (int s = 0; s < HID / 128; ++s) {
            int k0 = s * 128;
            // ---- GEMM1: h cols [32w, 32w+32) of this slab
            Frag wf[2][2];
            float b1v[2];
            #pragma unroll
            for (int nt = 0; nt < 2; ++nt) {
                int n = k0 + 32 * w + 16 * nt + lr;
                #pragma unroll
                for (int ks = 0; ks < 2; ++ks)
                    wf[nt][ks].q = *reinterpret_cast<const uint4*>(&W1T[(size_t)n * 64 + 32 * ks + 8 * lg]);
                b1v[nt] = b1[n];
            }
            f32x4_t h_acc[4][2];
            #pragma unroll
            for (int m = 0; m < 4; ++m)
                #pragma unroll
                for (int nt = 0; nt < 2; ++nt) h_acc[m][nt] = (f32x4_t){0.f, 0.f, 0.f, 0.f};
            #pragma unroll
            for (int m = 0; m < 4; ++m)
                #pragma unroll
                for (int nt = 0; nt < 2; ++nt) {
                    h_acc[m][nt] = __builtin_amdgcn_mfma_f32_16x16x32_bf16(xf[m][0].v, wf[nt][0].v, h_acc[m][nt], 0, 0, 0);
                    h_acc[m][nt] = __builtin_amdgcn_mfma_f32_16x16x32_bf16(xf[m][1].v, wf[nt][1].v, h_acc[m][nt], 0, 0, 0);
                }
            __syncthreads();   // previous slab's GEMM2 reads of h_lds done
            #pragma unroll
            for (int m = 0; m < 4; ++m)
                #pragma unroll
                for (int nt = 0; nt < 2; ++nt)
                    #pragma unroll
                    for (int r = 0; r < 4; ++r) {
                        int row = 16 * m + 4 * lg + r;
                        int col = 32 * w + 16 * nt + lr;
                        float v = fmaxf(h_acc[m][nt][r] + b1v[nt], 0.f);
                        h_lds[row][col] = bf16bits(v);
                    }
            __syncthreads();   // h slab ready
            // ---- GEMM2: rows [16w,16w+16), 5 N-tiles
            Frag a2[4];
            #pragma unroll
            for (int ks = 0; ks < 4; ++ks)
                a2[ks].q = *reinterpret_cast<const uint4*>(&h_lds[16 * w + lr][32 * ks + 8 * lg]);
            #pragma unroll
            for (int ks = 0; ks < 4; ++ks)
                #pragma unroll
                for (int nt = 0; nt < 5; ++nt) {
                    Frag bf;
                    int c = cmap[nt];
                    if (c >= 0) bf.q = *reinterpret_cast<const uint4*>(&W2T[(size_t)c * HID + k0 + 32 * ks + 8 * lg]);
                    else        bf.q = make_uint4(0u, 0u, 0u, 0u);
                    acc2[nt] = __builtin_amdgcn_mfma_f32_16x16x32_bf16(a2[ks].v, bf.v, acc2[nt], 0, 0, 0);
                }
        }

        // ---- epilogue: write tile (+bias) to LDS
        #pragma unroll
        for (int nt = 0; nt < 5; ++nt) {
            float bias;
            if (nt < 4)            bias = b2[16 * nt + lr];
            else if (lr < YD)      bias = b2[NK + g * YD + lr];
            else                   bias = 0.f;
            #pragma unroll
            for (int r = 0; r < 4; ++r)
                out_lds[16 * w + 4 * lg + r][16 * nt + lr] = acc2[nt][r] + bias;
        }
        __syncthreads();

        if (t < 64) {
            float ce_v = 0.f, mse_v = 0.f;
            if (t < nrows) {
                float m = -1e30f;
                for (int c = 0; c < NK; ++c) m = fmaxf(m, out_lds[t][c]);
                float s2 = 0.f;
                for (int c = 0; c < NK; ++c) s2 += expf(out_lds[t][c] - m);
                float lse = m + logf(s2);
                ce_v = lse - out_lds[t][g];
                int row = rows_s[t];
                #pragma unroll
                for (int j = 0; j < YD; ++j) {
                    float tr = y[row * YD + j] - centers[g * YD + j];
                    float d  = tr - out_lds[t][NK + j];
                    mse_v += d * d;
                }
            }
            red_ce[t] = ce_v; red_mse[t] = mse_v;
        }
        __syncthreads();
        if (t == 0) {
            float sc = 0.f, sm = 0.f;
            for (int i = 0; i < 64; ++i) { sc += red_ce[i]; sm += red_mse[i]; }
            atomicAdd(&accum[0], sc);
            atomicAdd(&accum[1], sm);
        }
        __syncthreads();
    }
}

__global__ void k_final(const float* __restrict__ accum, float* __restrict__ out) {
    out[0] = accum[0] / (float)B_N + 100.f * accum[1] / ((float)B_N * (float)YD);
}

extern "C" void kernel_launch(void* const* d_in, const int* in_sizes, int n_in,
                              void* d_out, int out_size, void* d_ws, size_t ws_size,
                              hipStream_t stream) {
    const float* x       = (const float*)d_in[0];
    const float* y       = (const float*)d_in[1];
    const float* centers = (const float*)d_in[2];
    const float* W1      = (const float*)d_in[3];
    const float* b1      = (const float*)d_in[4];
    const float* W2      = (const float*)d_in[5];
    const float* b2      = (const float*)d_in[6];

    char* ws = (char*)d_ws;
    float* accum  = (float*)ws;                        // 2 f32
    int* counts   = (int*)(ws + 256);                  // 64
    int* offsets  = (int*)(ws + 512);
    int* cursor   = (int*)(ws + 768);
    int* labels   = (int*)(ws + 4096);                 // B ints
    int* perm     = (int*)(ws + 4096 + 4 * B_N);
    unsigned short* W1T = (unsigned short*)(ws + 4096 + 8 * B_N);            // 2048*64 bf16
    unsigned short* W2T = (unsigned short*)(ws + 4096 + 8 * B_N + 262144);   // 704*2048 bf16

    hipMemsetAsync(ws, 0, 1024, stream);   // zero accum + counts
    k_labels <<<B_N / 256, 256, 0, stream>>>(y, centers, labels, counts);
    k_scan   <<<1, 64, 0, stream>>>(counts, offsets, cursor);
    k_scatter<<<B_N / 256, 256, 0, stream>>>(labels, cursor, perm);
    k_w1t    <<<HID / 256, 256, 0, stream>>>(W1, W1T);
    k_w2t    <<<dim3(OUTD / 32, HID / 32), 256, 0, stream>>>(W2, W2T);
    k_fused  <<<dim3(NK, TILES_Y), 256, 0, stream>>>(x, W1T, b1, W2T, b2, y, centers,
                                                     counts, offsets, perm, accum);
    k_final  <<<1, 1, 0, stream>>>(accum, (float*)d_out);
}

// Round 3
// 332.703 us; speedup vs baseline: 9.2032x; 1.8873x over previous
//
#include <hip/hip_runtime.h>
#include <hip/hip_bf16.h>
#include <math.h>

#define B_N    32768
#define XD     60
#define YD     10
#define NK     64
#define HID    2048
#define OUTD   704   // NK + NK*YD
#define MAXT   640   // >= max tiles (512 + 64 partials)

typedef __bf16 bf16x8_t __attribute__((ext_vector_type(8)));
typedef float  f32x4_t  __attribute__((ext_vector_type(4)));

union Frag { uint4 q; bf16x8_t v; };

__device__ __forceinline__ unsigned short bf16bits(float f) {
    __hip_bfloat16 h = __float2bfloat16(f);
    return *reinterpret_cast<unsigned short*>(&h);
}

// ---------------- labels: argmin_k ||y - c_k||^2  (ref formula, first-min ties)
__global__ __launch_bounds__(256) void k_labels(const float* __restrict__ y,
                                                const float* __restrict__ centers,
                                                int* __restrict__ labels,
                                                int* __restrict__ counts) {
    __shared__ float cs[NK * YD];
    __shared__ float sc[NK];
    int t = threadIdx.x;
    for (int idx = t; idx < NK * YD; idx += 256) cs[idx] = centers[idx];
    __syncthreads();
    if (t < NK) {
        float s = 0.f;
        for (int j = 0; j < YD; ++j) { float v = cs[t * YD + j]; s += v * v; }
        sc[t] = s;
    }
    __syncthreads();
    int i = blockIdx.x * 256 + t;
    if (i >= B_N) return;
    float ly[YD]; float sy = 0.f;
    for (int j = 0; j < YD; ++j) { ly[j] = y[i * YD + j]; sy += ly[j] * ly[j]; }
    float best = 1e30f; int lab = 0;
    for (int k = 0; k < NK; ++k) {
        float dot = 0.f;
        #pragma unroll
        for (int j = 0; j < YD; ++j) dot += ly[j] * cs[k * YD + j];
        float d = sy - 2.f * dot + sc[k];
        if (d < best) { best = d; lab = k; }
    }
    labels[i] = lab;
    atomicAdd(&counts[lab], 1);
}

// ---------------- serial scan + uniform tile-descriptor build
__global__ void k_scan(const int* __restrict__ counts, int* __restrict__ offsets,
                       int* __restrict__ cursor, int* __restrict__ tile_g,
                       int* __restrict__ tile_off, int* __restrict__ tile_n) {
    if (threadIdx.x != 0) return;
    int off = 0, nt = 0;
    for (int k = 0; k < NK; ++k) {
        offsets[k] = off; cursor[k] = off;
        int n = counts[k];
        for (int b = 0; b < n && nt < MAXT; b += 64) {
            tile_g[nt] = k; tile_off[nt] = off + b; tile_n[nt] = min(64, n - b); ++nt;
        }
        off += n;
    }
    for (; nt < MAXT; ++nt) tile_n[nt] = 0;
}

__global__ __launch_bounds__(256) void k_scatter(const int* __restrict__ labels,
                                                 int* __restrict__ cursor,
                                                 int* __restrict__ perm) {
    int i = blockIdx.x * 256 + threadIdx.x;
    if (i >= B_N) return;
    int pos = atomicAdd(&cursor[labels[i]], 1);
    perm[pos] = i;
}

// ---------------- W1T[n][k] = bf16(W1[10+k][n]), k in [0,64) padded past 60
__global__ __launch_bounds__(256) void k_w1t(const float* __restrict__ W1,
                                             unsigned short* __restrict__ W1T) {
    int n = blockIdx.x * 256 + threadIdx.x;
    #pragma unroll
    for (int k = 0; k < 64; ++k) {
        float v = (k < XD) ? W1[(size_t)(YD + k) * HID + n] : 0.f;
        W1T[(size_t)n * 64 + k] = bf16bits(v);
    }
}

// ---------------- W2T[c][k] = bf16(W2[k][c])  (704 x 2048 bf16)
__global__ __launch_bounds__(256) void k_w2t(const float* __restrict__ W2,
                                             unsigned short* __restrict__ W2T) {
    __shared__ float tile[32][33];
    int c0 = blockIdx.x * 32, k0 = blockIdx.y * 32;
    int tx = threadIdx.x & 31, ty = threadIdx.x >> 5;   // ty 0..7
    #pragma unroll
    for (int j = 0; j < 32; j += 8)
        tile[ty + j][tx] = W2[(size_t)(k0 + ty + j) * OUTD + c0 + tx];
    __syncthreads();
    #pragma unroll
    for (int j = 0; j < 32; j += 8)
        W2T[(size_t)(c0 + ty + j) * HID + k0 + tx] = bf16bits(tile[tx][ty + j]);
}

// ---------------- fused: one 64-row single-group tile per block
__global__ __launch_bounds__(256) void k_fused(const float* __restrict__ x,
                                               const unsigned short* __restrict__ W1T,
                                               const float* __restrict__ b1,
                                               const unsigned short* __restrict__ W2T,
                                               const float* __restrict__ b2,
                                               const float* __restrict__ y,
                                               const float* __restrict__ centers,
                                               const int* __restrict__ tile_g,
                                               const int* __restrict__ tile_off,
                                               const int* __restrict__ tile_n,
                                               const int* __restrict__ perm,
                                               float* __restrict__ accum) {
    __shared__ __align__(16) union {
        struct { unsigned short x[64][80]; unsigned short h[64][136]; } a;
        float out[64][85];
    } u;
    __shared__ int   rows_s[64];
    __shared__ float red_ce[64], red_mse[64];

    int bid   = blockIdx.x;
    int nrows = tile_n[bid];
    if (nrows == 0) return;
    int g   = tile_g[bid];
    int off = tile_off[bid];

    int t  = threadIdx.x;
    int w  = t >> 6;          // wave 0..3
    int l  = t & 63;
    int lr = l & 15;
    int lg = l >> 4;

    // per-lane W2T row indices for the 5 output N-tiles (64 logits + 10 res + pad)
    int cmap[5];
    #pragma unroll
    for (int nt = 0; nt < 4; ++nt) cmap[nt] = 16 * nt + lr;
    cmap[4] = NK + g * YD + ((lr < YD) ? lr : 0);   // cols 74..79 garbage, never read

    if (t < 64) rows_s[t] = (t < nrows) ? perm[off + t] : -1;
    __syncthreads();

    // gather x rows -> LDS bf16 (zero pad rows and cols >= 60)
    for (int idx = t; idx < 64 * 80; idx += 256) {
        int r = idx / 80, c = idx - r * 80;
        int row = rows_s[r];
        float v = (row >= 0 && c < XD) ? x[row * XD + c] : 0.f;
        u.a.x[r][c] = bf16bits(v);
    }
    __syncthreads();

    // x A-fragments, held across all slabs
    Frag xf[4][2];
    #pragma unroll
    for (int m = 0; m < 4; ++m)
        #pragma unroll
        for (int ks = 0; ks < 2; ++ks)
            xf[m][ks].q = *reinterpret_cast<const uint4*>(&u.a.x[16 * m + lr][32 * ks + 8 * lg]);

    f32x4_t acc2[5];
    #pragma unroll
    for (int nt = 0; nt < 5; ++nt) acc2[nt] = (f32x4_t){0.f, 0.f, 0.f, 0.f};

    for (int s = 0; s < HID / 128; ++s) {
        int k0 = s * 128;
        // ---- GEMM1: h cols [32w, 32w+32) of this slab
        Frag wf[2][2];
        float b1v[2];
        #pragma unroll
        for (int nt = 0; nt < 2; ++nt) {
            int n = k0 + 32 * w + 16 * nt + lr;
            #pragma unroll
            for (int ks = 0; ks < 2; ++ks)
                wf[nt][ks].q = *reinterpret_cast<const uint4*>(&W1T[(size_t)n * 64 + 32 * ks + 8 * lg]);
            b1v[nt] = b1[n];
        }
        f32x4_t h_acc[4][2];
        #pragma unroll
        for (int m = 0; m < 4; ++m)
            #pragma unroll
            for (int nt = 0; nt < 2; ++nt) h_acc[m][nt] = (f32x4_t){0.f, 0.f, 0.f, 0.f};
        #pragma unroll
        for (int m = 0; m < 4; ++m)
            #pragma unroll
            for (int nt = 0; nt < 2; ++nt) {
                h_acc[m][nt] = __builtin_amdgcn_mfma_f32_16x16x32_bf16(xf[m][0].v, wf[nt][0].v, h_acc[m][nt], 0, 0, 0);
                h_acc[m][nt] = __builtin_amdgcn_mfma_f32_16x16x32_bf16(xf[m][1].v, wf[nt][1].v, h_acc[m][nt], 0, 0, 0);
            }
        __syncthreads();   // previous slab's GEMM2 reads of h done
        #pragma unroll
        for (int m = 0; m < 4; ++m)
            #pragma unroll
            for (int nt = 0; nt < 2; ++nt)
                #pragma unroll
                for (int r = 0; r < 4; ++r) {
                    int row = 16 * m + 4 * lg + r;
                    int col = 32 * w + 16 * nt + lr;
                    float v = fmaxf(h_acc[m][nt][r] + b1v[nt], 0.f);
                    u.a.h[row][col] = bf16bits(v);
                }
        __syncthreads();   // h slab ready
        // ---- GEMM2: rows [16w,16w+16), 5 N-tiles
        Frag a2[4];
        #pragma unroll
        for (int ks = 0; ks < 4; ++ks)
            a2[ks].q = *reinterpret_cast<const uint4*>(&u.a.h[16 * w + lr][32 * ks + 8 * lg]);
        #pragma unroll
        for (int ks = 0; ks < 4; ++ks)
            #pragma unroll
            for (int nt = 0; nt < 5; ++nt) {
                Frag bf;
                bf.q = *reinterpret_cast<const uint4*>(&W2T[(size_t)cmap[nt] * HID + k0 + 32 * ks + 8 * lg]);
                acc2[nt] = __builtin_amdgcn_mfma_f32_16x16x32_bf16(a2[ks].v, bf.v, acc2[nt], 0, 0, 0);
            }
    }
    __syncthreads();   // all h reads done before overlaying u.out

    // ---- epilogue: write tile (+bias) into u.out
    #pragma unroll
    for (int nt = 0; nt < 5; ++nt) {
        float bias;
        if (nt < 4)       bias = b2[16 * nt + lr];
        else if (lr < YD) bias = b2[NK + g * YD + lr];
        else              bias = 0.f;
        #pragma unroll
        for (int r = 0; r < 4; ++r)
            u.out[16 * w + 4 * lg + r][16 * nt + lr] = acc2[nt][r] + bias;
    }
    __syncthreads();

    if (t < 64) {
        float ce_v = 0.f, mse_v = 0.f;
        if (t < nrows) {
            float m = -1e30f;
            for (int c = 0; c < NK; ++c) m = fmaxf(m, u.out[t][c]);
            float s2 = 0.f;
            for (int c = 0; c < NK; ++c) s2 += expf(u.out[t][c] - m);
            float lse = m + logf(s2);
            ce_v = lse - u.out[t][g];
            int row = rows_s[t];
            #pragma unroll
            for (int j = 0; j < YD; ++j) {
                float tr = y[row * YD + j] - centers[g * YD + j];
                float d  = tr - u.out[t][NK + j];
                mse_v += d * d;
            }
        }
        red_ce[t] = ce_v; red_mse[t] = mse_v;
    }
    __syncthreads();
    if (t == 0) {
        float sc = 0.f, sm = 0.f;
        for (int i = 0; i < 64; ++i) { sc += red_ce[i]; sm += red_mse[i]; }
        atomicAdd(&accum[0], sc);
        atomicAdd(&accum[1], sm);
    }
}

__global__ void k_final(const float* __restrict__ accum, float* __restrict__ out) {
    out[0] = accum[0] / (float)B_N + 100.f * accum[1] / ((float)B_N * (float)YD);
}

extern "C" void kernel_launch(void* const* d_in, const int* in_sizes, int n_in,
                              void* d_out, int out_size, void* d_ws, size_t ws_size,
                              hipStream_t stream) {
    const float* x       = (const float*)d_in[0];
    const float* y       = (const float*)d_in[1];
    const float* centers = (const float*)d_in[2];
    const float* W1      = (const float*)d_in[3];
    const float* b1      = (const float*)d_in[4];
    const float* W2      = (const float*)d_in[5];
    const float* b2      = (const float*)d_in[6];

    char* ws = (char*)d_ws;
    float* accum  = (float*)ws;                        // 2 f32
    int* counts   = (int*)(ws + 256);                  // 64
    int* offsets  = (int*)(ws + 512);
    int* cursor   = (int*)(ws + 768);
    int* tile_g   = (int*)(ws + 1024);                 // 640
    int* tile_off = (int*)(ws + 1024 + 4 * MAXT);
    int* tile_n   = (int*)(ws + 1024 + 8 * MAXT);
    char* ws2     = ws + 1024 + 12 * MAXT + 256;
    int* labels   = (int*)ws2;                         // B ints
    int* perm     = (int*)(ws2 + 4 * B_N);
    unsigned short* W1T = (unsigned short*)(ws2 + 8 * B_N);            // 2048*64 bf16
    unsigned short* W2T = (unsigned short*)(ws2 + 8 * B_N + 262144);   // 704*2048 bf16

    hipMemsetAsync(ws, 0, 1024, stream);   // zero accum + counts
    k_labels <<<B_N / 256, 256, 0, stream>>>(y, centers, labels, counts);
    k_scan   <<<1, 64, 0, stream>>>(counts, offsets, cursor, tile_g, tile_off, tile_n);
    k_scatter<<<B_N / 256, 256, 0, stream>>>(labels, cursor, perm);
    k_w1t    <<<HID / 256, 256, 0, stream>>>(W1, W1T);
    k_w2t    <<<dim3(OUTD / 32, HID / 32), 256, 0, stream>>>(W2, W2T);
    k_fused  <<<dim3(576), 256, 0, stream>>>(x, W1T, b1, W2T, b2, y, centers,
                                             tile_g, tile_off, tile_n, perm, accum);
    k_final  <<<1, 1, 0, stream>>>(accum, (float*)d_out);
}

// Round 4
// 261.281 us; speedup vs baseline: 11.7190x; 1.2734x over previous
//
#include <hip/hip_runtime.h>
#include <hip/hip_bf16.h>
#include <math.h>

#define B_N    32768
#define XD     60
#define YD     10
#define NK     64
#define HID    2048
#define OUTD   704   // NK + NK*YD
#define MAXT   640   // >= max tiles (512 + 64 partials)
#define HP     136   // h_lds pitch (bf16 elems) — 272B row: 16B aligned, optimal b64-write banking

typedef __bf16 bf16x8_t __attribute__((ext_vector_type(8)));
typedef float  f32x4_t  __attribute__((ext_vector_type(4)));

union Frag { uint4 q; bf16x8_t v; };

__device__ __forceinline__ unsigned short bf16bits(float f) {
    __hip_bfloat16 h = __float2bfloat16(f);
    return *reinterpret_cast<unsigned short*>(&h);
}

// ---------------- labels: argmin_k ||y - c_k||^2  (ref formula, first-min ties)
__global__ __launch_bounds__(256) void k_labels(const float* __restrict__ y,
                                                const float* __restrict__ centers,
                                                int* __restrict__ labels,
                                                int* __restrict__ counts) {
    __shared__ float cs[NK * YD];
    __shared__ float sc[NK];
    int t = threadIdx.x;
    for (int idx = t; idx < NK * YD; idx += 256) cs[idx] = centers[idx];
    __syncthreads();
    if (t < NK) {
        float s = 0.f;
        for (int j = 0; j < YD; ++j) { float v = cs[t * YD + j]; s += v * v; }
        sc[t] = s;
    }
    __syncthreads();
    int i = blockIdx.x * 256 + t;
    if (i >= B_N) return;
    float ly[YD]; float sy = 0.f;
    for (int j = 0; j < YD; ++j) { ly[j] = y[i * YD + j]; sy += ly[j] * ly[j]; }
    float best = 1e30f; int lab = 0;
    for (int k = 0; k < NK; ++k) {
        float dot = 0.f;
        #pragma unroll
        for (int j = 0; j < YD; ++j) dot += ly[j] * cs[k * YD + j];
        float d = sy - 2.f * dot + sc[k];
        if (d < best) { best = d; lab = k; }
    }
    labels[i] = lab;
    atomicAdd(&counts[lab], 1);
}

// ---------------- parallel scan + tile-descriptor build (1 wave of 64)
__global__ void k_scan(const int* __restrict__ counts, int* __restrict__ offsets,
                       int* __restrict__ cursor, int* __restrict__ tile_g,
                       int* __restrict__ tile_off, int* __restrict__ tile_n) {
    int t = threadIdx.x;            // 64 threads = 1 wave
    int c = counts[t];
    int ntm = (c + 63) >> 6;
    int sc = c, st = ntm;
    #pragma unroll
    for (int d = 1; d < 64; d <<= 1) {
        int vc = __shfl_up(sc, d);
        int vt = __shfl_up(st, d);
        if (t >= d) { sc += vc; st += vt; }
    }
    int off   = sc - c;             // exclusive prefix of counts
    int tbase = st - ntm;           // exclusive prefix of tile counts
    offsets[t] = off; cursor[t] = off;
    for (int i = 0; i < ntm; ++i) {
        tile_g[tbase + i]   = t;
        tile_off[tbase + i] = off + 64 * i;
        tile_n[tbase + i]   = min(64, c - 64 * i);
    }
    int total = __shfl(st, 63);
    for (int i = total + t; i < MAXT; i += 64) tile_n[i] = 0;
}

__global__ __launch_bounds__(256) void k_scatter(const int* __restrict__ labels,
                                                 int* __restrict__ cursor,
                                                 int* __restrict__ perm) {
    int i = blockIdx.x * 256 + threadIdx.x;
    if (i >= B_N) return;
    int pos = atomicAdd(&cursor[labels[i]], 1);
    perm[pos] = i;
}

// ---------------- W1T[n][k] = bf16(W1[10+k][n]), k in [0,64) padded past 60
__global__ __launch_bounds__(256) void k_w1t(const float* __restrict__ W1,
                                             unsigned short* __restrict__ W1T) {
    __shared__ float tile[32][33];
    int n0 = blockIdx.x * 32, k0 = blockIdx.y * 32;
    int tx = threadIdx.x & 31, ty = threadIdx.x >> 5;   // ty 0..7
    #pragma unroll
    for (int j = 0; j < 32; j += 8) {
        int k = k0 + ty + j;
        tile[ty + j][tx] = (k < XD) ? W1[(size_t)(YD + k) * HID + n0 + tx] : 0.f;
    }
    __syncthreads();
    #pragma unroll
    for (int j = 0; j < 32; j += 8)
        W1T[(size_t)(n0 + ty + j) * 64 + k0 + tx] = bf16bits(tile[tx][ty + j]);
}

// ---------------- W2T[c][k] = bf16(W2[k][c])  (704 x 2048 bf16)
__global__ __launch_bounds__(256) void k_w2t(const float* __restrict__ W2,
                                             unsigned short* __restrict__ W2T) {
    __shared__ float tile[32][33];
    int c0 = blockIdx.x * 32, k0 = blockIdx.y * 32;
    int tx = threadIdx.x & 31, ty = threadIdx.x >> 5;
    #pragma unroll
    for (int j = 0; j < 32; j += 8)
        tile[ty + j][tx] = W2[(size_t)(k0 + ty + j) * OUTD + c0 + tx];
    __syncthreads();
    #pragma unroll
    for (int j = 0; j < 32; j += 8)
        W2T[(size_t)(c0 + ty + j) * HID + k0 + tx] = bf16bits(tile[tx][ty + j]);
}

// ---------------- fused: one 64-row single-group tile per block.
// GEMM1 hid-split over waves; GEMM2 K-split over waves (no redundant W2 loads).
// Both MFMAs operand-swapped so D holds contiguous-in-reg output -> vector LDS stores.
__global__ __launch_bounds__(256) void k_fused(const float* __restrict__ x,
                                               const unsigned short* __restrict__ W1T,
                                               const float* __restrict__ b1,
                                               const unsigned short* __restrict__ W2T,
                                               const float* __restrict__ b2,
                                               const float* __restrict__ y,
                                               const float* __restrict__ centers,
                                               const int* __restrict__ tile_g,
                                               const int* __restrict__ tile_off,
                                               const int* __restrict__ tile_n,
                                               const int* __restrict__ perm,
                                               float* __restrict__ accum) {
    __shared__ __align__(16) union {
        struct { unsigned short x[64][80]; unsigned short h[64][HP]; } a;  // 10240 + 17408 B
        float out[64][84];                                                 // 21504 B
    } u;
    __shared__ int   rows_s[64];
    __shared__ float red_ce[64], red_mse[64];

    int bid   = blockIdx.x;
    int nrows = tile_n[bid];
    if (nrows == 0) return;
    int g   = tile_g[bid];
    int off = tile_off[bid];

    int t  = threadIdx.x;
    int w  = t >> 6;          // wave 0..3
    int l  = t & 63;
    int lr = l & 15;
    int lg = l >> 4;

    // W2T row (= output col) indices loaded by this lane for the 5 N-tiles
    int cmap[5];
    #pragma unroll
    for (int nt = 0; nt < 4; ++nt) cmap[nt] = 16 * nt + lr;
    cmap[4] = NK + g * YD + ((lr < YD) ? lr : 0);   // out rows 74..79 garbage, never read

    if (t < 64) rows_s[t] = (t < nrows) ? perm[off + t] : -1;
    __syncthreads();

    // gather x rows -> LDS bf16 (zero pad rows and cols >= 60)
    for (int idx = t; idx < 64 * 80; idx += 256) {
        int r = idx / 80, c = idx - r * 80;
        int row = rows_s[r];
        float v = (row >= 0 && c < XD) ? x[row * XD + c] : 0.f;
        u.a.x[r][c] = bf16bits(v);
    }
    __syncthreads();

    // x fragments (B-operand of swapped GEMM1), held across all slabs
    Frag xf[4][2];
    #pragma unroll
    for (int mt = 0; mt < 4; ++mt)
        #pragma unroll
        for (int ks = 0; ks < 2; ++ks)
            xf[mt][ks].q = *reinterpret_cast<const uint4*>(&u.a.x[16 * mt + lr][32 * ks + 8 * lg]);

    // full-tile accumulator, K-partial per wave: [m-tile][n-tile]
    f32x4_t acc2[4][5];
    #pragma unroll
    for (int mt = 0; mt < 4; ++mt)
        #pragma unroll
        for (int nt = 0; nt < 5; ++nt) acc2[mt][nt] = (f32x4_t){0.f, 0.f, 0.f, 0.f};

    for (int s = 0; s < HID / 128; ++s) {
        int k0 = s * 128;
        // ---- issue ALL weight loads for this slab up front (latency hides under GEMM1+barriers)
        Frag wf[2][2]; float b1v[2];
        #pragma unroll
        for (int n2 = 0; n2 < 2; ++n2) {
            int n = k0 + 32 * w + 16 * n2 + lr;
            #pragma unroll
            for (int ks = 0; ks < 2; ++ks)
                wf[n2][ks].q = *reinterpret_cast<const uint4*>(&W1T[(size_t)n * 64 + 32 * ks + 8 * lg]);
            b1v[n2] = b1[n];
        }
        Frag bf[5];
        #pragma unroll
        for (int nt = 0; nt < 5; ++nt)
            bf[nt].q = *reinterpret_cast<const uint4*>(&W2T[(size_t)cmap[nt] * HID + k0 + 32 * w + 8 * lg]);

        // ---- GEMM1 (swapped): D = W1s^T-tile x x-tile -> lane holds 4 consecutive hid for row m=lr
        f32x4_t hacc[4][2];
        #pragma unroll
        for (int mt = 0; mt < 4; ++mt)
            #pragma unroll
            for (int n2 = 0; n2 < 2; ++n2) hacc[mt][n2] = (f32x4_t){0.f, 0.f, 0.f, 0.f};
        #pragma unroll
        for (int mt = 0; mt < 4; ++mt)
            #pragma unroll
            for (int n2 = 0; n2 < 2; ++n2) {
                hacc[mt][n2] = __builtin_amdgcn_mfma_f32_16x16x32_bf16(wf[n2][0].v, xf[mt][0].v, hacc[mt][n2], 0, 0, 0);
                hacc[mt][n2] = __builtin_amdgcn_mfma_f32_16x16x32_bf16(wf[n2][1].v, xf[mt][1].v, hacc[mt][n2], 0, 0, 0);
            }
        __syncthreads();   // previous slab's h reads complete
        #pragma unroll
        for (int mt = 0; mt < 4; ++mt)
            #pragma unroll
            for (int n2 = 0; n2 < 2; ++n2) {
                ushort4 p;
                p.x = bf16bits(fmaxf(hacc[mt][n2][0] + b1v[n2], 0.f));
                p.y = bf16bits(fmaxf(hacc[mt][n2][1] + b1v[n2], 0.f));
                p.z = bf16bits(fmaxf(hacc[mt][n2][2] + b1v[n2], 0.f));
                p.w = bf16bits(fmaxf(hacc[mt][n2][3] + b1v[n2], 0.f));
                *reinterpret_cast<ushort4*>(&u.a.h[16 * mt + lr][32 * w + 16 * n2 + 4 * lg]) = p;
            }
        __syncthreads();   // h slab ready
        // ---- GEMM2 (swapped, K-split): wave w consumes k-slice [32w, 32w+32)
        Frag a2[4];
        #pragma unroll
        for (int mt = 0; mt < 4; ++mt)
            a2[mt].q = *reinterpret_cast<const uint4*>(&u.a.h[16 * mt + lr][32 * w + 8 * lg]);
        #pragma unroll
        for (int mt = 0; mt < 4; ++mt)
            #pragma unroll
            for (int nt = 0; nt < 5; ++nt)
                acc2[mt][nt] = __builtin_amdgcn_mfma_f32_16x16x32_bf16(bf[nt].v, a2[mt].v, acc2[mt][nt], 0, 0, 0);
    }
    __syncthreads();   // all h/x reads done before overlaying u.out

    // ---- epilogue: sum the 4 K-partials via 4 barrier phases of float4 adds
    for (int wv = 0; wv < 4; ++wv) {
        if (w == wv) {
            #pragma unroll
            for (int mt = 0; mt < 4; ++mt)
                #pragma unroll
                for (int nt = 0; nt < 5; ++nt) {
                    float4 v;
                    v.x = acc2[mt][nt][0]; v.y = acc2[mt][nt][1];
                    v.z = acc2[mt][nt][2]; v.w = acc2[mt][nt][3];
                    float4* p = reinterpret_cast<float4*>(&u.out[16 * mt + lr][16 * nt + 4 * lg]);
                    if (wv == 0) {
                        float bx, by, bz, bw;
                        if (nt < 4) {
                            int c = 16 * nt + 4 * lg;
                            bx = b2[c]; by = b2[c + 1]; bz = b2[c + 2]; bw = b2[c + 3];
                        } else {
                            int c = 4 * lg;
                            bx = (c     < YD) ? b2[NK + g * YD + c]     : 0.f;
                            by = (c + 1 < YD) ? b2[NK + g * YD + c + 1] : 0.f;
                            bz = (c + 2 < YD) ? b2[NK + g * YD + c + 2] : 0.f;
                            bw = (c + 3 < YD) ? b2[NK + g * YD + c + 3] : 0.f;
                        }
                        v.x += bx; v.y += by; v.z += bz; v.w += bw;
                        *p = v;
                    } else {
                        float4 cur = *p;
                        cur.x += v.x; cur.y += v.y; cur.z += v.z; cur.w += v.w;
                        *p = cur;
                    }
                }
        }
        __syncthreads();
    }

    if (t < 64) {
        float ce_v = 0.f, mse_v = 0.f;
        if (t < nrows) {
            float m = -1e30f;
            for (int c = 0; c < NK; ++c) m = fmaxf(m, u.out[t][c]);
            float s2 = 0.f;
            for (int c = 0; c < NK; ++c) s2 += expf(u.out[t][c] - m);
            float lse = m + logf(s2);
            ce_v = lse - u.out[t][g];
            int row = rows_s[t];
            #pragma unroll
            for (int j = 0; j < YD; ++j) {
                float tr = y[row * YD + j] - centers[g * YD + j];
                float d  = tr - u.out[t][NK + j];
                mse_v += d * d;
            }
        }
        red_ce[t] = ce_v; red_mse[t] = mse_v;
    }
    __syncthreads();
    if (t == 0) {
        float sc = 0.f, sm = 0.f;
        for (int i = 0; i < 64; ++i) { sc += red_ce[i]; sm += red_mse[i]; }
        atomicAdd(&accum[0], sc);
        atomicAdd(&accum[1], sm);
    }
}

__global__ void k_final(const float* __restrict__ accum, float* __restrict__ out) {
    out[0] = accum[0] / (float)B_N + 100.f * accum[1] / ((float)B_N * (float)YD);
}

extern "C" void kernel_launch(void* const* d_in, const int* in_sizes, int n_in,
                              void* d_out, int out_size, void* d_ws, size_t ws_size,
                              hipStream_t stream) {
    const float* x       = (const float*)d_in[0];
    const float* y       = (const float*)d_in[1];
    const float* centers = (const float*)d_in[2];
    const float* W1      = (const float*)d_in[3];
    const float* b1      = (const float*)d_in[4];
    const float* W2      = (const float*)d_in[5];
    const float* b2      = (const float*)d_in[6];

    char* ws = (char*)d_ws;
    float* accum  = (float*)ws;                        // 2 f32
    int* counts   = (int*)(ws + 256);                  // 64
    int* offsets  = (int*)(ws + 512);
    int* cursor   = (int*)(ws + 768);
    int* tile_g   = (int*)(ws + 1024);                 // MAXT
    int* tile_off = (int*)(ws + 1024 + 4 * MAXT);
    int* tile_n   = (int*)(ws + 1024 + 8 * MAXT);
    char* ws2     = ws + 1024 + 12 * MAXT + 256;
    int* labels   = (int*)ws2;                         // B ints
    int* perm     = (int*)(ws2 + 4 * B_N);
    unsigned short* W1T = (unsigned short*)(ws2 + 8 * B_N);            // 2048*64 bf16
    unsigned short* W2T = (unsigned short*)(ws2 + 8 * B_N + 262144);   // 704*2048 bf16

    hipMemsetAsync(ws, 0, 1024, stream);   // zero accum + counts
    k_labels <<<B_N / 256, 256, 0, stream>>>(y, centers, labels, counts);
    k_scan   <<<1, 64, 0, stream>>>(counts, offsets, cursor, tile_g, tile_off, tile_n);
    k_scatter<<<B_N / 256, 256, 0, stream>>>(labels, cursor, perm);
    k_w1t    <<<dim3(HID / 32, 2), 256, 0, stream>>>(W1, W1T);
    k_w2t    <<<dim3(OUTD / 32, HID / 32), 256, 0, stream>>>(W2, W2T);
    k_fused  <<<dim3(576), 256, 0, stream>>>(x, W1T, b1, W2T, b2, y, centers,
                                             tile_g, tile_off, tile_n, perm, accum);
    k_final  <<<1, 1, 0, stream>>>(accum, (float*)d_out);
}

// Round 5
// 138.003 us; speedup vs baseline: 22.1875x; 1.8933x over previous
//
#include <hip/hip_runtime.h>
#include <hip/hip_bf16.h>
#include <math.h>

#define B_N    32768
#define XD     60
#define YD     10
#define NK     64
#define HID    2048
#define OUTD   704   // NK + NK*YD
#define TS     32    // rows per tile
#define MAXT   1152  // >= 1024 full tiles + 64 partials, = k_fused grid
#define HP     136   // h_lds pitch (bf16)

#define LBLK   128   // label blocks (B/256)
#define W1BLK  128   // 64 n-tiles x 2 k-tiles
#define W2BLK  1408  // 22 c-tiles x 64 k-tiles

typedef __bf16 bf16x8_t __attribute__((ext_vector_type(8)));
typedef float  f32x4_t  __attribute__((ext_vector_type(4)));

union Frag { uint4 q; bf16x8_t v; };

__device__ __forceinline__ unsigned short bf16bits(float f) {
    __hip_bfloat16 h = __float2bfloat16(f);
    return *reinterpret_cast<unsigned short*>(&h);
}

// ---------------- merged prep: labels+counts | W1T | W2T (independent jobs)
__global__ __launch_bounds__(256) void k_prep(const float* __restrict__ y,
                                              const float* __restrict__ centers,
                                              const float* __restrict__ W1,
                                              const float* __restrict__ W2,
                                              int* __restrict__ labels,
                                              int* __restrict__ counts,
                                              unsigned short* __restrict__ W1T,
                                              unsigned short* __restrict__ W2T) {
    __shared__ float smem[1056];
    int bid = blockIdx.x, t = threadIdx.x;
    if (bid < LBLK) {
        float* cs = smem; float* sc = smem + 640; int* lh = (int*)(smem + 704);
        for (int i = t; i < NK * YD; i += 256) cs[i] = centers[i];
        if (t < NK) lh[t] = 0;
        __syncthreads();
        if (t < NK) { float s = 0.f; for (int j = 0; j < YD; ++j) { float v = cs[t*YD+j]; s += v*v; } sc[t] = s; }
        __syncthreads();
        int i = bid * 256 + t;
        float ly[YD]; float sy = 0.f;
        for (int j = 0; j < YD; ++j) { ly[j] = y[i*YD+j]; sy += ly[j]*ly[j]; }
        float best = 1e30f; int lab = 0;
        for (int k = 0; k < NK; ++k) {
            float dot = 0.f;
            #pragma unroll
            for (int j = 0; j < YD; ++j) dot += ly[j] * cs[k*YD+j];
            float d = sy - 2.f*dot + sc[k];
            if (d < best) { best = d; lab = k; }
        }
        labels[i] = lab;
        atomicAdd(&lh[lab], 1);
        __syncthreads();
        if (t < NK && lh[t] > 0) atomicAdd(&counts[t], lh[t]);
    } else if (bid < LBLK + W1BLK) {
        int b = bid - LBLK;
        float (*tile)[33] = (float(*)[33])smem;
        int n0 = (b >> 1) * 32, k0 = (b & 1) * 32;
        int tx = t & 31, ty = t >> 5;
        #pragma unroll
        for (int j = 0; j < 32; j += 8) {
            int k = k0 + ty + j;
            tile[ty+j][tx] = (k < XD) ? W1[(size_t)(YD + k) * HID + n0 + tx] : 0.f;
        }
        __syncthreads();
        #pragma unroll
        for (int j = 0; j < 32; j += 8)
            W1T[(n0 + ty + j) * 64 + k0 + tx] = bf16bits(tile[tx][ty+j]);
    } else {
        int b = bid - LBLK - W1BLK;
        float (*tile)[33] = (float(*)[33])smem;
        int c0 = (b % 22) * 32, k0 = (b / 22) * 32;
        int tx = t & 31, ty = t >> 5;
        #pragma unroll
        for (int j = 0; j < 32; j += 8)
            tile[ty+j][tx] = W2[(size_t)(k0 + ty + j) * OUTD + c0 + tx];
        __syncthreads();
        #pragma unroll
        for (int j = 0; j < 32; j += 8)
            W2T[(c0 + ty + j) * HID + k0 + tx] = bf16bits(tile[tx][ty+j]);
    }
}

// ---------------- wave-parallel scan + tile-descriptor build
__global__ void k_scan(const int* __restrict__ counts, int* __restrict__ cursor,
                       int* __restrict__ tile_g, int* __restrict__ tile_off,
                       int* __restrict__ tile_n) {
    int t = threadIdx.x;            // 64 threads = 1 wave
    int c = counts[t];
    int ntm = (c + TS - 1) / TS;
    int sc = c, st = ntm;
    #pragma unroll
    for (int d = 1; d < 64; d <<= 1) {
        int vc = __shfl_up(sc, d);
        int vt = __shfl_up(st, d);
        if (t >= d) { sc += vc; st += vt; }
    }
    int off   = sc - c;
    int tbase = st - ntm;
    cursor[t] = off;
    for (int i = 0; i < ntm; ++i) {
        tile_g[tbase + i]   = t;
        tile_off[tbase + i] = off + TS * i;
        tile_n[tbase + i]   = min(TS, c - TS * i);
    }
    int total = __shfl(st, 63);
    for (int i = total + t; i < MAXT; i += 64) tile_n[i] = 0;
}

// ---------------- scatter: LDS ranks + one base-claim per (block,label)
__global__ __launch_bounds__(256) void k_scatter(const int* __restrict__ labels,
                                                 int* __restrict__ cursor,
                                                 int* __restrict__ perm) {
    __shared__ int lh[NK], lbase[NK];
    int t = threadIdx.x;
    if (t < NK) lh[t] = 0;
    __syncthreads();
    int i = blockIdx.x * 256 + t;
    int lab = labels[i];
    int rank = atomicAdd(&lh[lab], 1);
    __syncthreads();
    if (t < NK && lh[t] > 0) lbase[t] = atomicAdd(&cursor[t], lh[t]);
    __syncthreads();
    perm[lbase[lab] + rank] = i;
}

__device__ __forceinline__ void finalize(float* accum, int* ticket, float* out, int nb) {
    __threadfence();
    int old = atomicAdd(ticket, 1);
    if (old == nb - 1) {
        float ce = atomicAdd(&accum[0], 0.f);
        float ms = atomicAdd(&accum[1], 0.f);
        out[0] = ce / (float)B_N + 100.f * ms / ((float)B_N * (float)YD);
    }
}

// ---------------- fused: one 32-row single-group tile per block, 4 waves.
// GEMM1 hid-split over waves; GEMM2 K-split over waves; h double-buffered (1 barrier/slab).
__global__ __launch_bounds__(256, 4) void k_fused(const float* __restrict__ x,
                                                  const unsigned short* __restrict__ W1T,
                                                  const float* __restrict__ b1,
                                                  const unsigned short* __restrict__ W2T,
                                                  const float* __restrict__ b2,
                                                  const float* __restrict__ y,
                                                  const float* __restrict__ centers,
                                                  const int* __restrict__ tile_g,
                                                  const int* __restrict__ tile_off,
                                                  const int* __restrict__ tile_n,
                                                  const int* __restrict__ perm,
                                                  float* __restrict__ accum,
                                                  int* __restrict__ ticket,
                                                  float* __restrict__ out) {
    __shared__ __align__(16) union {
        struct { unsigned short x[TS][80]; unsigned short h[2][TS][HP]; } a;  // 5120 + 17408 B
        float o[TS][84];                                                      // 10752 B
    } u;
    __shared__ int   rows_s[TS];
    __shared__ float red_ce[TS], red_mse[TS];

    int bid = blockIdx.x, t = threadIdx.x;
    int nrows = tile_n[bid];
    if (nrows == 0) { if (t == 0) finalize(accum, ticket, out, (int)gridDim.x); return; }
    int g   = tile_g[bid];
    int off = tile_off[bid];

    int w  = t >> 6;          // wave 0..3
    int l  = t & 63;
    int lr = l & 15;
    int lg = l >> 4;

    if (t < TS) rows_s[t] = (t < nrows) ? perm[off + t] : -1;
    __syncthreads();

    // gather x rows -> LDS bf16 (zero pad rows and cols >= 60)
    for (int idx = t; idx < TS * 80; idx += 256) {
        int r = idx / 80, c = idx - r * 80;
        int row = rows_s[r];
        float v = (row >= 0 && c < XD) ? x[row * XD + c] : 0.f;
        u.a.x[r][c] = bf16bits(v);
    }
    __syncthreads();

    // x fragments (B-operand of swapped GEMM1), slab-invariant
    Frag xf[2][2];
    #pragma unroll
    for (int mt = 0; mt < 2; ++mt)
        #pragma unroll
        for (int ks = 0; ks < 2; ++ks)
            xf[mt][ks].q = *reinterpret_cast<const uint4*>(&u.a.x[16*mt + lr][32*ks + 8*lg]);

    // W2T element offsets for the 5 N-tiles (64 logits + 10 res + pad)
    int cofs[5];
    #pragma unroll
    for (int nt = 0; nt < 4; ++nt) cofs[nt] = (16*nt + lr) * HID;
    cofs[4] = (NK + g * YD + ((lr < YD) ? lr : 0)) * HID;

    f32x4_t acc2[2][5];
    #pragma unroll
    for (int mt = 0; mt < 2; ++mt)
        #pragma unroll
        for (int nt = 0; nt < 5; ++nt) acc2[mt][nt] = (f32x4_t){0.f, 0.f, 0.f, 0.f};

    int p = 0;
    for (int s = 0; s < HID / 128; ++s) {
        int k0 = s * 128;
        // issue all weight loads for this slab up front
        Frag wf[2][2]; float b1v[2];
        #pragma unroll
        for (int n2 = 0; n2 < 2; ++n2) {
            int n = k0 + 32*w + 16*n2 + lr;
            #pragma unroll
            for (int ks = 0; ks < 2; ++ks)
                wf[n2][ks].q = *reinterpret_cast<const uint4*>(&W1T[n * 64 + 32*ks + 8*lg]);
            b1v[n2] = b1[n];
        }
        Frag bf[5];
        #pragma unroll
        for (int nt = 0; nt < 5; ++nt)
            bf[nt].q = *reinterpret_cast<const uint4*>(&W2T[cofs[nt] + k0 + 32*w + 8*lg]);

        // GEMM1 (swapped): wave w computes hid cols [32w, 32w+32)
        f32x4_t hacc[2][2];
        #pragma unroll
        for (int mt = 0; mt < 2; ++mt)
            #pragma unroll
            for (int n2 = 0; n2 < 2; ++n2) hacc[mt][n2] = (f32x4_t){0.f, 0.f, 0.f, 0.f};
        #pragma unroll
        for (int mt = 0; mt < 2; ++mt)
            #pragma unroll
            for (int n2 = 0; n2 < 2; ++n2) {
                hacc[mt][n2] = __builtin_amdgcn_mfma_f32_16x16x32_bf16(wf[n2][0].v, xf[mt][0].v, hacc[mt][n2], 0, 0, 0);
                hacc[mt][n2] = __builtin_amdgcn_mfma_f32_16x16x32_bf16(wf[n2][1].v, xf[mt][1].v, hacc[mt][n2], 0, 0, 0);
            }
        // write h slab into buffer p (prev reads of p separated by barrier s-1)
        #pragma unroll
        for (int mt = 0; mt < 2; ++mt)
            #pragma unroll
            for (int n2 = 0; n2 < 2; ++n2) {
                ushort4 pk;
                pk.x = bf16bits(fmaxf(hacc[mt][n2][0] + b1v[n2], 0.f));
                pk.y = bf16bits(fmaxf(hacc[mt][n2][1] + b1v[n2], 0.f));
                pk.z = bf16bits(fmaxf(hacc[mt][n2][2] + b1v[n2], 0.f));
                pk.w = bf16bits(fmaxf(hacc[mt][n2][3] + b1v[n2], 0.f));
                *reinterpret_cast<ushort4*>(&u.a.h[p][16*mt + lr][32*w + 16*n2 + 4*lg]) = pk;
            }
        __syncthreads();   // h[p] ready; also fences reads of h[p^1] from last slab
        // GEMM2 (swapped, K-split): wave w consumes k-slice [32w, 32w+32)
        Frag a2[2];
        #pragma unroll
        for (int mt = 0; mt < 2; ++mt)
            a2[mt].q = *reinterpret_cast<const uint4*>(&u.a.h[p][16*mt + lr][32*w + 8*lg]);
        #pragma unroll
        for (int mt = 0; mt < 2; ++mt)
            #pragma unroll
            for (int nt = 0; nt < 5; ++nt)
                acc2[mt][nt] = __builtin_amdgcn_mfma_f32_16x16x32_bf16(bf[nt].v, a2[mt].v, acc2[mt][nt], 0, 0, 0);
        p ^= 1;
    }
    __syncthreads();   // all h/x reads done before overlaying u.o

    // epilogue: sum 4 K-partials, bias in phase 0
    for (int wv = 0; wv < 4; ++wv) {
        if (w == wv) {
            #pragma unroll
            for (int mt = 0; mt < 2; ++mt)
                #pragma unroll
                for (int nt = 0; nt < 5; ++nt) {
                    float4 v;
                    v.x = acc2[mt][nt][0]; v.y = acc2[mt][nt][1];
                    v.z = acc2[mt][nt][2]; v.w = acc2[mt][nt][3];
                    float4* pp = reinterpret_cast<float4*>(&u.o[16*mt + lr][16*nt + 4*lg]);
                    if (wv == 0) {
                        float bx, by, bz, bw;
                        if (nt < 4) {
                            int c = 16*nt + 4*lg;
                            bx = b2[c]; by = b2[c+1]; bz = b2[c+2]; bw = b2[c+3];
                        } else {
                            int c = 4*lg;
                            bx = (c   < YD) ? b2[NK + g*YD + c  ] : 0.f;
                            by = (c+1 < YD) ? b2[NK + g*YD + c+1] : 0.f;
                            bz = (c+2 < YD) ? b2[NK + g*YD + c+2] : 0.f;
                            bw = (c+3 < YD) ? b2[NK + g*YD + c+3] : 0.f;
                        }
                        v.x += bx; v.y += by; v.z += bz; v.w += bw;
                        *pp = v;
                    } else {
                        float4 cur = *pp;
                        cur.x += v.x; cur.y += v.y; cur.z += v.z; cur.w += v.w;
                        *pp = cur;
                    }
                }
        }
        __syncthreads();
    }

    if (t < TS) {
        float ce_v = 0.f, mse_v = 0.f;
        if (t < nrows) {
            float m = -1e30f;
            for (int c = 0; c < NK; ++c) m = fmaxf(m, u.o[t][c]);
            float s2 = 0.f;
            for (int c = 0; c < NK; ++c) s2 += expf(u.o[t][c] - m);
            float lse = m + logf(s2);
            ce_v = lse - u.o[t][g];
            int row = rows_s[t];
            #pragma unroll
            for (int j = 0; j < YD; ++j) {
                float tr = y[row * YD + j] - centers[g * YD + j];
                float d  = tr - u.o[t][NK + j];
                mse_v += d * d;
            }
        }
        red_ce[t] = ce_v; red_mse[t] = mse_v;
    }
    __syncthreads();
    if (t == 0) {
        float sc = 0.f, sm = 0.f;
        for (int i = 0; i < TS; ++i) { sc += red_ce[i]; sm += red_mse[i]; }
        atomicAdd(&accum[0], sc);
        atomicAdd(&accum[1], sm);
        finalize(accum, ticket, out, (int)gridDim.x);
    }
}

extern "C" void kernel_launch(void* const* d_in, const int* in_sizes, int n_in,
                              void* d_out, int out_size, void* d_ws, size_t ws_size,
                              hipStream_t stream) {
    const float* x       = (const float*)d_in[0];
    const float* y       = (const float*)d_in[1];
    const float* centers = (const float*)d_in[2];
    const float* W1      = (const float*)d_in[3];
    const float* b1      = (const float*)d_in[4];
    const float* W2      = (const float*)d_in[5];
    const float* b2      = (const float*)d_in[6];

    char* ws = (char*)d_ws;
    float* accum  = (float*)ws;                        // 2 f32 @ 0
    int* ticket   = (int*)(ws + 128);
    int* counts   = (int*)(ws + 256);                  // 64 ints
    int* cursor   = (int*)(ws + 768);
    int* tile_g   = (int*)(ws + 1024);                 // MAXT
    int* tile_off = (int*)(ws + 1024 + 4 * MAXT);
    int* tile_n   = (int*)(ws + 1024 + 8 * MAXT);
    char* ws2     = ws + 1024 + 12 * MAXT + 256;
    int* labels   = (int*)ws2;                         // B ints
    int* perm     = (int*)(ws2 + 4 * B_N);
    unsigned short* W1T = (unsigned short*)(ws2 + 8 * B_N);            // 2048*64 bf16
    unsigned short* W2T = (unsigned short*)(ws2 + 8 * B_N + 262144);   // 704*2048 bf16

    hipMemsetAsync(ws, 0, 1024, stream);   // zero accum + ticket + counts
    k_prep   <<<LBLK + W1BLK + W2BLK, 256, 0, stream>>>(y, centers, W1, W2,
                                                        labels, counts, W1T, W2T);
    k_scan   <<<1, 64, 0, stream>>>(counts, cursor, tile_g, tile_off, tile_n);
    k_scatter<<<B_N / 256, 256, 0, stream>>>(labels, cursor, perm);
    k_fused  <<<MAXT, 256, 0, stream>>>(x, W1T, b1, W2T, b2, y, centers,
                                        tile_g, tile_off, tile_n, perm, accum,
                                        ticket, (float*)d_out);
}

// Round 6
// 108.869 us; speedup vs baseline: 28.1250x; 1.2676x over previous
//
#include <hip/hip_runtime.h>
#include <hip/hip_bf16.h>
#include <math.h>

#define B_N    32768
#define XD     60
#define YD     10
#define NK     64
#define HID    2048
#define OUTD   704   // NK + NK*YD
#define TS     32    // rows per tile
#define MAXT   1152  // >= 1024 full tiles + 64 partials, = k_fused grid
#define HP     136   // h_lds pitch (bf16)

#define LBLK   128   // label blocks (B/256)

typedef __bf16 bf16x8_t __attribute__((ext_vector_type(8)));
typedef float  f32x4_t  __attribute__((ext_vector_type(4)));

union Frag { uint4 q; bf16x8_t v; };

__device__ __forceinline__ unsigned short bf16bits(float f) {
    __hip_bfloat16 h = __float2bfloat16(f);
    return *reinterpret_cast<unsigned short*>(&h);
}

// ---------------- merged prep: labels+counts | W1P | W2P | W2G packs
// Fragment-major packing: record (s,w,frag) holds 64 lanes x 16B contiguous,
// so k_fused weight loads are base + lane*16B (fully coalesced).
__global__ __launch_bounds__(256) void k_prep(const float* __restrict__ y,
                                              const float* __restrict__ centers,
                                              const float* __restrict__ W1,
                                              const float* __restrict__ W2,
                                              int* __restrict__ labels,
                                              int* __restrict__ counts,
                                              unsigned short* __restrict__ W1P,
                                              unsigned short* __restrict__ W2P,
                                              unsigned short* __restrict__ W2G) {
    __shared__ __align__(16) char smem[40960];
    int bid = blockIdx.x, t = threadIdx.x;
    int l  = t & 63;
    int lr = l & 15;
    int lg = l >> 4;

    if (bid < LBLK) {
        // ---- labels
        float* cs = (float*)smem; float* sc = cs + 640; int* lh = (int*)(cs + 704);
        for (int i = t; i < NK * YD; i += 256) cs[i] = centers[i];
        if (t < NK) lh[t] = 0;
        __syncthreads();
        if (t < NK) { float s = 0.f; for (int j = 0; j < YD; ++j) { float v = cs[t*YD+j]; s += v*v; } sc[t] = s; }
        __syncthreads();
        int i = bid * 256 + t;
        float ly[YD]; float sy = 0.f;
        for (int j = 0; j < YD; ++j) { ly[j] = y[i*YD+j]; sy += ly[j]*ly[j]; }
        float best = 1e30f; int lab = 0;
        for (int k = 0; k < NK; ++k) {
            float dot = 0.f;
            #pragma unroll
            for (int j = 0; j < YD; ++j) dot += ly[j] * cs[k*YD+j];
            float d = sy - 2.f*dot + sc[k];
            if (d < best) { best = d; lab = k; }
        }
        labels[i] = lab;
        atomicAdd(&lh[lab], 1);
        __syncthreads();
        if (t < NK && lh[t] > 0) atomicAdd(&counts[t], lh[t]);
    } else if (bid < LBLK + 64) {
        // ---- W1P: record(s,w,n2,ks): lane(l) elem j = bf16(W1[10+32ks+8lg+j][128s+32w+16n2+lr])
        int b = bid - LBLK, s = b >> 2, w = b & 3;
        unsigned short (*lds)[32] = (unsigned short(*)[32])smem;  // [k 0..63][n 0..31]
        int n0 = 128*s + 32*w;
        for (int idx = t; idx < 64*32; idx += 256) {
            int kk = idx >> 5, c = idx & 31;
            float v = (kk < XD) ? W1[(size_t)(YD + kk) * HID + n0 + c] : 0.f;
            lds[kk][c] = bf16bits(v);
        }
        __syncthreads();
        int n2 = t >> 7, ks = (t >> 6) & 1;
        ushort2 o[4];
        #pragma unroll
        for (int jj = 0; jj < 4; ++jj) {
            o[jj].x = lds[32*ks + 8*lg + 2*jj    ][16*n2 + lr];
            o[jj].y = lds[32*ks + 8*lg + 2*jj + 1][16*n2 + lr];
        }
        *reinterpret_cast<uint4*>(&W1P[((((s*4 + w)*2 + n2)*2 + ks) << 9) + l*8]) =
            *reinterpret_cast<uint4*>(o);
    } else if (bid < LBLK + 128) {
        // ---- W2P (logit cols): record(s,w,nt): lane elem j = bf16(W2[128s+32w+8lg+j][16nt+lr])
        int b = bid - LBLK - 64, s = b >> 2, w = b & 3;
        unsigned short (*lds)[64] = (unsigned short(*)[64])smem;  // [k 0..31][c 0..63]
        int k0 = 128*s + 32*w;
        for (int idx = t; idx < 32*64; idx += 256) {
            int kk = idx >> 6, c = idx & 63;
            lds[kk][c] = bf16bits(W2[(size_t)(k0 + kk) * OUTD + c]);
        }
        __syncthreads();
        int nt = t >> 6;
        ushort2 o[4];
        #pragma unroll
        for (int jj = 0; jj < 4; ++jj) {
            o[jj].x = lds[8*lg + 2*jj    ][16*nt + lr];
            o[jj].y = lds[8*lg + 2*jj + 1][16*nt + lr];
        }
        *reinterpret_cast<uint4*>(&W2P[(((s*4 + w)*4 + nt) << 9) + l*8]) =
            *reinterpret_cast<uint4*>(o);
    } else {
        // ---- W2G (group cols): record(g,s,w): lane elem j = bf16(W2[128s+32w+8lg+j][64+10g+lr]) (lr<10)
        int b = bid - LBLK - 128, s = b >> 2, w = b & 3;
        unsigned short (*lds)[640] = (unsigned short(*)[640])smem; // [k 0..31][c 0..639]
        int k0 = 128*s + 32*w;
        for (int idx = t; idx < 32*640; idx += 256) {
            int kk = idx / 640, c = idx - kk*640;
            lds[kk][c] = bf16bits(W2[(size_t)(k0 + kk) * OUTD + NK + c]);
        }
        __syncthreads();
        for (int g = t >> 6; g < 64; g += 4) {
            ushort2 o[4];
            #pragma unroll
            for (int jj = 0; jj < 4; ++jj) {
                o[jj].x = (lr < YD) ? lds[8*lg + 2*jj    ][10*g + lr] : (unsigned short)0;
                o[jj].y = (lr < YD) ? lds[8*lg + 2*jj + 1][10*g + lr] : (unsigned short)0;
            }
            *reinterpret_cast<uint4*>(&W2G[(((g*16 + s)*4 + w) << 9) + l*8]) =
                *reinterpret_cast<uint4*>(o);
        }
    }
}

// ---------------- wave-parallel scan + tile-descriptor build
__global__ void k_scan(const int* __restrict__ counts, int* __restrict__ cursor,
                       int* __restrict__ tile_g, int* __restrict__ tile_off,
                       int* __restrict__ tile_n) {
    int t = threadIdx.x;            // 64 threads = 1 wave
    int c = counts[t];
    int ntm = (c + TS - 1) / TS;
    int sc = c, st = ntm;
    #pragma unroll
    for (int d = 1; d < 64; d <<= 1) {
        int vc = __shfl_up(sc, d);
        int vt = __shfl_up(st, d);
        if (t >= d) { sc += vc; st += vt; }
    }
    int off   = sc - c;
    int tbase = st - ntm;
    cursor[t] = off;
    for (int i = 0; i < ntm; ++i) {
        tile_g[tbase + i]   = t;
        tile_off[tbase + i] = off + TS * i;
        tile_n[tbase + i]   = min(TS, c - TS * i);
    }
    int total = __shfl(st, 63);
    for (int i = total + t; i < MAXT; i += 64) tile_n[i] = 0;
}

// ---------------- scatter: LDS ranks + one base-claim per (block,label)
__global__ __launch_bounds__(256) void k_scatter(const int* __restrict__ labels,
                                                 int* __restrict__ cursor,
                                                 int* __restrict__ perm) {
    __shared__ int lh[NK], lbase[NK];
    int t = threadIdx.x;
    if (t < NK) lh[t] = 0;
    __syncthreads();
    int i = blockIdx.x * 256 + t;
    int lab = labels[i];
    int rank = atomicAdd(&lh[lab], 1);
    __syncthreads();
    if (t < NK && lh[t] > 0) lbase[t] = atomicAdd(&cursor[t], lh[t]);
    __syncthreads();
    perm[lbase[lab] + rank] = i;
}

__device__ __forceinline__ void finalize(float* accum, int* ticket, float* out, int nb) {
    __threadfence();
    int old = atomicAdd(ticket, 1);
    if (old == nb - 1) {
        float ce = atomicAdd(&accum[0], 0.f);
        float ms = atomicAdd(&accum[1], 0.f);
        out[0] = ce / (float)B_N + 100.f * ms / ((float)B_N * (float)YD);
    }
}

// ---------------- fused: one 32-row single-group tile per block, 4 waves.
// GEMM1 hid-split over waves; GEMM2 K-split over waves; h double-buffered.
// All weight loads are packed fragment records: base + lane*16B (coalesced).
__global__ __launch_bounds__(256, 4) void k_fused(const float* __restrict__ x,
                                                  const unsigned short* __restrict__ W1P,
                                                  const float* __restrict__ b1,
                                                  const unsigned short* __restrict__ W2P,
                                                  const unsigned short* __restrict__ W2G,
                                                  const float* __restrict__ b2,
                                                  const float* __restrict__ y,
                                                  const float* __restrict__ centers,
                                                  const int* __restrict__ tile_g,
                                                  const int* __restrict__ tile_off,
                                                  const int* __restrict__ tile_n,
                                                  const int* __restrict__ perm,
                                                  float* __restrict__ accum,
                                                  int* __restrict__ ticket,
                                                  float* __restrict__ out) {
    __shared__ __align__(16) union {
        struct { unsigned short x[TS][80]; unsigned short h[2][TS][HP]; } a;
        float o[TS][84];
    } u;
    __shared__ int   rows_s[TS];
    __shared__ float red_ce[TS], red_mse[TS];

    int bid = blockIdx.x, t = threadIdx.x;
    int nrows = tile_n[bid];
    if (nrows == 0) { if (t == 0) finalize(accum, ticket, out, (int)gridDim.x); return; }
    int g   = tile_g[bid];
    int off = tile_off[bid];

    int w  = t >> 6;          // wave 0..3
    int l  = t & 63;
    int lr = l & 15;
    int lg = l >> 4;

    if (t < TS) rows_s[t] = (t < nrows) ? perm[off + t] : -1;
    __syncthreads();

    // gather x rows -> LDS bf16 (zero pad rows and cols >= 60)
    for (int idx = t; idx < TS * 80; idx += 256) {
        int r = idx / 80, c = idx - r * 80;
        int row = rows_s[r];
        float v = (row >= 0 && c < XD) ? x[row * XD + c] : 0.f;
        u.a.x[r][c] = bf16bits(v);
    }
    __syncthreads();

    // x fragments (B-operand of swapped GEMM1), slab-invariant
    Frag xf[2][2];
    #pragma unroll
    for (int mt = 0; mt < 2; ++mt)
        #pragma unroll
        for (int ks = 0; ks < 2; ++ks)
            xf[mt][ks].q = *reinterpret_cast<const uint4*>(&u.a.x[16*mt + lr][32*ks + 8*lg]);

    f32x4_t acc2[2][5];
    #pragma unroll
    for (int mt = 0; mt < 2; ++mt)
        #pragma unroll
        for (int nt = 0; nt < 5; ++nt) acc2[mt][nt] = (f32x4_t){0.f, 0.f, 0.f, 0.f};

    int p = 0;
    for (int s = 0; s < HID / 128; ++s) {
        int k0 = s * 128;
        // ---- packed weight loads (coalesced: base + l*16B)
        Frag wf[2][2]; float b1v[2];
        int f1 = (((s*4 + w)*2) << 10) + l*8;        // (s,w,n2=0,ks=0) record base
        wf[0][0].q = *reinterpret_cast<const uint4*>(&W1P[f1]);
        wf[0][1].q = *reinterpret_cast<const uint4*>(&W1P[f1 + 512]);
        wf[1][0].q = *reinterpret_cast<const uint4*>(&W1P[f1 + 1024]);
        wf[1][1].q = *reinterpret_cast<const uint4*>(&W1P[f1 + 1536]);
        #pragma unroll
        for (int n2 = 0; n2 < 2; ++n2) b1v[n2] = b1[k0 + 32*w + 16*n2 + lr];

        Frag bf[5];
        int f2 = (((s*4 + w)*4) << 9) + l*8;
        #pragma unroll
        for (int nt = 0; nt < 4; ++nt)
            bf[nt].q = *reinterpret_cast<const uint4*>(&W2P[f2 + nt*512]);
        bf[4].q = *reinterpret_cast<const uint4*>(&W2G[(((g*16 + s)*4 + w) << 9) + l*8]);

        // ---- GEMM1 (swapped): wave w computes hid cols [32w, 32w+32)
        f32x4_t hacc[2][2];
        #pragma unroll
        for (int mt = 0; mt < 2; ++mt)
            #pragma unroll
            for (int n2 = 0; n2 < 2; ++n2) hacc[mt][n2] = (f32x4_t){0.f, 0.f, 0.f, 0.f};
        #pragma unroll
        for (int mt = 0; mt < 2; ++mt)
            #pragma unroll
            for (int n2 = 0; n2 < 2; ++n2) {
                hacc[mt][n2] = __builtin_amdgcn_mfma_f32_16x16x32_bf16(wf[n2][0].v, xf[mt][0].v, hacc[mt][n2], 0, 0, 0);
                hacc[mt][n2] = __builtin_amdgcn_mfma_f32_16x16x32_bf16(wf[n2][1].v, xf[mt][1].v, hacc[mt][n2], 0, 0, 0);
            }
        #pragma unroll
        for (int mt = 0; mt < 2; ++mt)
            #pragma unroll
            for (int n2 = 0; n2 < 2; ++n2) {
                ushort4 pk;
                pk.x = bf16bits(fmaxf(hacc[mt][n2][0] + b1v[n2], 0.f));
                pk.y = bf16bits(fmaxf(hacc[mt][n2][1] + b1v[n2], 0.f));
                pk.z = bf16bits(fmaxf(hacc[mt][n2][2] + b1v[n2], 0.f));
                pk.w = bf16bits(fmaxf(hacc[mt][n2][3] + b1v[n2], 0.f));
                *reinterpret_cast<ushort4*>(&u.a.h[p][16*mt + lr][32*w + 16*n2 + 4*lg]) = pk;
            }
        __syncthreads();   // h[p] ready; also fences reads of h[p^1] from last slab
        // ---- GEMM2 (swapped, K-split): wave w consumes k-slice [32w, 32w+32)
        Frag a2[2];
        #pragma unroll
        for (int mt = 0; mt < 2; ++mt)
            a2[mt].q = *reinterpret_cast<const uint4*>(&u.a.h[p][16*mt + lr][32*w + 8*lg]);
        #pragma unroll
        for (int mt = 0; mt < 2; ++mt)
            #pragma unroll
            for (int nt = 0; nt < 5; ++nt)
                acc2[mt][nt] = __builtin_amdgcn_mfma_f32_16x16x32_bf16(bf[nt].v, a2[mt].v, acc2[mt][nt], 0, 0, 0);
        p ^= 1;
    }
    __syncthreads();   // all h/x reads done before overlaying u.o

    // epilogue: sum 4 K-partials, bias in phase 0
    for (int wv = 0; wv < 4; ++wv) {
        if (w == wv) {
            #pragma unroll
            for (int mt = 0; mt < 2; ++mt)
                #pragma unroll
                for (int nt = 0; nt < 5; ++nt) {
                    float4 v;
                    v.x = acc2[mt][nt][0]; v.y = acc2[mt][nt][1];
                    v.z = acc2[mt][nt][2]; v.w = acc2[mt][nt][3];
                    float4* pp = reinterpret_cast<float4*>(&u.o[16*mt + lr][16*nt + 4*lg]);
                    if (wv == 0) {
                        float bx, by, bz, bw;
                        if (nt < 4) {
                            int c = 16*nt + 4*lg;
                            bx = b2[c]; by = b2[c+1]; bz = b2[c+2]; bw = b2[c+3];
                        } else {
                            int c = 4*lg;
                            bx = (c   < YD) ? b2[NK + g*YD + c  ] : 0.f;
                            by = (c+1 < YD) ? b2[NK + g*YD + c+1] : 0.f;
                            bz = (c+2 < YD) ? b2[NK + g*YD + c+2] : 0.f;
                            bw = (c+3 < YD) ? b2[NK + g*YD + c+3] : 0.f;
                        }
                        v.x += bx; v.y += by; v.z += bz; v.w += bw;
                        *pp = v;
                    } else {
                        float4 cur = *pp;
                        cur.x += v.x; cur.y += v.y; cur.z += v.z; cur.w += v.w;
                        *pp = cur;
                    }
                }
        }
        __syncthreads();
    }

    if (t < TS) {
        float ce_v = 0.f, mse_v = 0.f;
        if (t < nrows) {
            float m = -1e30f;
            for (int c = 0; c < NK; ++c) m = fmaxf(m, u.o[t][c]);
            float s2 = 0.f;
            for (int c = 0; c < NK; ++c) s2 += expf(u.o[t][c] - m);
            float lse = m + logf(s2);
            ce_v = lse - u.o[t][g];
            int row = rows_s[t];
            #pragma unroll
            for (int j = 0; j < YD; ++j) {
                float tr = y[row * YD + j] - centers[g * YD + j];
                float d  = tr - u.o[t][NK + j];
                mse_v += d * d;
            }
        }
        red_ce[t] = ce_v; red_mse[t] = mse_v;
    }
    __syncthreads();
    if (t == 0) {
        float sc = 0.f, sm = 0.f;
        for (int i = 0; i < TS; ++i) { sc += red_ce[i]; sm += red_mse[i]; }
        atomicAdd(&accum[0], sc);
        atomicAdd(&accum[1], sm);
        finalize(accum, ticket, out, (int)gridDim.x);
    }
}

extern "C" void kernel_launch(void* const* d_in, const int* in_sizes, int n_in,
                              void* d_out, int out_size, void* d_ws, size_t ws_size,
                              hipStream_t stream) {
    const float* x       = (const float*)d_in[0];
    const float* y       = (const float*)d_in[1];
    const float* centers = (const float*)d_in[2];
    const float* W1      = (const float*)d_in[3];
    const float* b1      = (const float*)d_in[4];
    const float* W2      = (const float*)d_in[5];
    const float* b2      = (const float*)d_in[6];

    char* ws = (char*)d_ws;
    float* accum  = (float*)ws;                        // 2 f32 @ 0
    int* ticket   = (int*)(ws + 128);
    int* counts   = (int*)(ws + 256);                  // 64 ints
    int* cursor   = (int*)(ws + 768);
    int* tile_g   = (int*)(ws + 1024);                 // MAXT
    int* tile_off = (int*)(ws + 1024 + 4 * MAXT);
    int* tile_n   = (int*)(ws + 1024 + 8 * MAXT);
    char* ws2     = ws + 1024 + 12 * MAXT + 256;
    int* labels   = (int*)ws2;                               // 128 KB
    int* perm     = (int*)(ws2 + 131072);                    // 128 KB
    unsigned short* W1P = (unsigned short*)(ws2 + 262144);   // 256 KB
    unsigned short* W2P = (unsigned short*)(ws2 + 524288);   // 256 KB
    unsigned short* W2G = (unsigned short*)(ws2 + 786432);   // 4 MB

    hipMemsetAsync(ws, 0, 1024, stream);   // zero accum + ticket + counts
    k_prep   <<<LBLK + 192, 256, 0, stream>>>(y, centers, W1, W2,
                                              labels, counts, W1P, W2P, W2G);
    k_scan   <<<1, 64, 0, stream>>>(counts, cursor, tile_g, tile_off, tile_n);
    k_scatter<<<B_N / 256, 256, 0, stream>>>(labels, cursor, perm);
    k_fused  <<<MAXT, 256, 0, stream>>>(x, W1P, b1, W2P, W2G, b2, y, centers,
                                        tile_g, tile_off, tile_n, perm, accum,
                                        ticket, (float*)d_out);
}